// Round 5
// baseline (380.425 us; speedup 1.0000x reference)
//
#include <hip/hip_runtime.h>
#include <hip/hip_bf16.h>
#include <math.h>

#define N_PTS 8192
#define KNN 8
#define JSPLIT 16
#define WAVES 4
#define IB_BLOCK (WAVES * 16)            // 64 query rows per block
#define JCHUNK (N_PTS / JSPLIT)          // 512 candidates per (wave, js)
#define NPART ((N_PTS / IB_BLOCK) * JSPLIT)  // 2048 count partials

typedef __attribute__((ext_vector_type(8))) short bf16x8;
typedef __attribute__((ext_vector_type(4))) float f32x4;

__device__ __forceinline__ float med3(float a, float b, float c) {
    return __builtin_amdgcn_fmed3f(a, b, c);
}

// Branchless insert of v into ascending sorted d[0..7], dropping the largest:
// d0' = min(v,d0); dk' = med3(v, d[k-1], d[k]).  8 VALU ops, no control flow.
__device__ __forceinline__ void insertv(float v, float (&d)[8]) {
    float p = d[0];
    d[0] = fminf(v, d[0]);
#pragma unroll
    for (int k = 1; k < 8; ++k) {
        float q = d[k];
        d[k] = med3(v, p, q);
        p = q;
    }
}

// Fused prep: one wave per row. Exact fp32 row-norm + bf16 conversion.
template <int D>
__global__ __launch_bounds__(256) void prep_kernel(const float* __restrict__ x,
                                                   __hip_bfloat16* __restrict__ xb,
                                                   float* __restrict__ sq) {
    const int row = (blockIdx.x * 256 + threadIdx.x) >> 6;
    const int lane = threadIdx.x & 63;
    float s = 0.f;
    if constexpr (D == 128) {
        float2 v = *reinterpret_cast<const float2*>(x + (size_t)row * D + lane * 2);
        s = fmaf(v.x, v.x, v.y * v.y);
        __hip_bfloat162 h = __float22bfloat162_rn(v);
        *reinterpret_cast<__hip_bfloat162*>(xb + (size_t)row * D + lane * 2) = h;
    } else {
        float v = (lane < D) ? x[(size_t)row * D + lane] : 0.f;
        s = v * v;
        if (lane < D) xb[(size_t)row * D + lane] = __float2bfloat16(v);
    }
#pragma unroll
    for (int o = 32; o > 0; o >>= 1) s += __shfl_down(s, o);
    if (lane == 0) sq[row] = s;
}

// Phase 1: value-only top-8 scan -> per-(row, js) sorted 8 smallest distances.
// C layout (16x16x32 bf16): col = lane&15 (query i), row = (lane>>4)*4 + reg (cand j).
template <int D>
__global__ __launch_bounds__(256, 4) void thresh_scan(const __hip_bfloat16* __restrict__ xb,
                                                      const float* __restrict__ sq,
                                                      float* __restrict__ pd) {
    constexpr int KB = D / 32;
    const int lane = threadIdx.x & 63;
    const int w = __builtin_amdgcn_readfirstlane((int)(threadIdx.x >> 6));
    const int ib = blockIdx.x * IB_BLOCK + w * 16;
    const int js = blockIdx.y;
    const int jbase = js * JCHUNK;
    const int lrow = lane & 15;
    const int lk = (lane >> 4) * 8;
    const int jr = (lane >> 4) * 4;

    bf16x8 bfrag[KB];
#pragma unroll
    for (int kb = 0; kb < KB; ++kb)
        bfrag[kb] = *reinterpret_cast<const bf16x8*>(xb + (size_t)(ib + lrow) * D + kb * 32 + lk);

    float d8[8];
#pragma unroll
    for (int k = 0; k < 8; ++k) d8[k] = __builtin_inff();

#pragma unroll 2
    for (int jt = jbase; jt < jbase + JCHUNK; jt += 16) {
        f32x4 acc = {0.f, 0.f, 0.f, 0.f};
#pragma unroll
        for (int kb = 0; kb < KB; ++kb) {
            bf16x8 afrag = *reinterpret_cast<const bf16x8*>(xb + (size_t)(jt + lrow) * D + kb * 32 + lk);
            acc = __builtin_amdgcn_mfma_f32_16x16x32_bf16(afrag, bfrag[kb], acc, 0, 0, 0);
        }
        // dist(j,i) = sq[j] - 2*dot  (sq[i] dropped: row-constant, order-safe)
        f32x4 sq4 = *reinterpret_cast<const f32x4*>(sq + jt + jr);
        if (jt == ib) {  // diagonal tile: mask self (wave-uniform branch)
#pragma unroll
            for (int r = 0; r < 4; ++r) {
                float dist = fmaf(-2.f, acc[r], sq4[r]);
                if (jr + r == lrow) dist = __builtin_inff();
                insertv(dist, d8);
            }
        } else {
#pragma unroll
            for (int r = 0; r < 4; ++r) insertv(fmaf(-2.f, acc[r], sq4[r]), d8);
        }
    }

    // Merge the 4 lanes holding each column: lanes {i, i+16, i+32, i+48}.
    __shared__ float lds_d[WAVES][64][8];
#pragma unroll
    for (int k = 0; k < 8; ++k) lds_d[w][lane][k] = d8[k];
    __syncthreads();
    if (lane < 16) {
        float e[8];
#pragma unroll
        for (int k = 0; k < 8; ++k) e[k] = lds_d[w][lane][k];
#pragma unroll
        for (int p = 1; p < 4; ++p)
#pragma unroll
            for (int k = 0; k < 8; ++k) insertv(lds_d[w][p * 16 + lane][k], e);
        const size_t o = ((size_t)(ib + lane) * JSPLIT + js) * 8;
#pragma unroll
        for (int k = 0; k < 8; ++k) pd[o + k] = e[k];
    }
}

// Merge JSPLIT partial value-lists per row -> threshold t(row) = 8th smallest.
__global__ __launch_bounds__(256) void thresh_merge(const float* __restrict__ pd,
                                                    float* __restrict__ t) {
    const int row = blockIdx.x * 256 + threadIdx.x;
    const f32x4* p = reinterpret_cast<const f32x4*>(pd + (size_t)row * (JSPLIT * 8));
    float d8[8];
#pragma unroll
    for (int k = 0; k < 8; ++k) d8[k] = __builtin_inff();
    for (int l = 0; l < JSPLIT * 2; ++l) {
        f32x4 v = p[l];
        insertv(v[0], d8); insertv(v[1], d8); insertv(v[2], d8); insertv(v[3], d8);
    }
    t[row] = d8[7];
}

// Phase 2: recompute distances (bitwise-identical MFMA+fmaf path) for X and Z
// jointly; count pairs below both row-thresholds. No index tracking anywhere.
__global__ __launch_bounds__(256, 4) void count_scan(const __hip_bfloat16* __restrict__ bX,
                                                     const float* __restrict__ sqX,
                                                     const float* __restrict__ tX,
                                                     const __hip_bfloat16* __restrict__ bZ,
                                                     const float* __restrict__ sqZ,
                                                     const float* __restrict__ tZ,
                                                     int* __restrict__ partial) {
    const int lane = threadIdx.x & 63;
    const int w = __builtin_amdgcn_readfirstlane((int)(threadIdx.x >> 6));
    const int ib = blockIdx.x * IB_BLOCK + w * 16;
    const int js = blockIdx.y;
    const int jbase = js * JCHUNK;
    const int lrow = lane & 15;
    const int lk = (lane >> 4) * 8;
    const int jr = (lane >> 4) * 4;

    bf16x8 bfX[4];
#pragma unroll
    for (int kb = 0; kb < 4; ++kb)
        bfX[kb] = *reinterpret_cast<const bf16x8*>(bX + (size_t)(ib + lrow) * 128 + kb * 32 + lk);
    bf16x8 bfZ = *reinterpret_cast<const bf16x8*>(bZ + (size_t)(ib + lrow) * 32 + lk);
    const float tx = tX[ib + lrow];
    const float tz = tZ[ib + lrow];

    int c = 0;
#pragma unroll 2
    for (int jt = jbase; jt < jbase + JCHUNK; jt += 16) {
        f32x4 accX = {0.f, 0.f, 0.f, 0.f};
#pragma unroll
        for (int kb = 0; kb < 4; ++kb) {
            bf16x8 af = *reinterpret_cast<const bf16x8*>(bX + (size_t)(jt + lrow) * 128 + kb * 32 + lk);
            accX = __builtin_amdgcn_mfma_f32_16x16x32_bf16(af, bfX[kb], accX, 0, 0, 0);
        }
        f32x4 accZ = {0.f, 0.f, 0.f, 0.f};
        {
            bf16x8 af = *reinterpret_cast<const bf16x8*>(bZ + (size_t)(jt + lrow) * 32 + lk);
            accZ = __builtin_amdgcn_mfma_f32_16x16x32_bf16(af, bfZ, accZ, 0, 0, 0);
        }
        f32x4 sx4 = *reinterpret_cast<const f32x4*>(sqX + jt + jr);
        f32x4 sz4 = *reinterpret_cast<const f32x4*>(sqZ + jt + jr);
        if (jt == ib) {  // diagonal tile: exclude j == i
#pragma unroll
            for (int r = 0; r < 4; ++r) {
                float dx = fmaf(-2.f, accX[r], sx4[r]);
                float dz = fmaf(-2.f, accZ[r], sz4[r]);
                c += (dx <= tx && dz <= tz && (jr + r != lrow)) ? 1 : 0;
            }
        } else {
#pragma unroll
            for (int r = 0; r < 4; ++r) {
                float dx = fmaf(-2.f, accX[r], sx4[r]);
                float dz = fmaf(-2.f, accZ[r], sz4[r]);
                c += (dx <= tx && dz <= tz) ? 1 : 0;
            }
        }
    }

#pragma unroll
    for (int o = 32; o > 0; o >>= 1) c += __shfl_down(c, o);
    __shared__ int wsum[WAVES];
    if (lane == 0) wsum[w] = c;
    __syncthreads();
    if (threadIdx.x == 0)
        partial[blockIdx.y * (N_PTS / IB_BLOCK) + blockIdx.x] = wsum[0] + wsum[1] + wsum[2] + wsum[3];
}

__global__ void finalize_kernel(const int* __restrict__ partial, float* __restrict__ out) {
    int v = 0;
    for (int k = threadIdx.x; k < NPART; k += 256) v += partial[k];
#pragma unroll
    for (int o = 32; o > 0; o >>= 1) v += __shfl_down(v, o);
    __shared__ int wsum[4];
    if ((threadIdx.x & 63) == 0) wsum[threadIdx.x >> 6] = v;
    __syncthreads();
    if (threadIdx.x == 0) {
        // loss = 100 * (2*K*N - 2*matches) / N^2  (exact in double)
        double m = (double)(wsum[0] + wsum[1] + wsum[2] + wsum[3]);
        out[0] = (float)((2.0 * KNN * N_PTS - 2.0 * m) * 100.0 / ((double)N_PTS * (double)N_PTS));
    }
}

extern "C" void kernel_launch(void* const* d_in, const int* in_sizes, int n_in,
                              void* d_out, int out_size, void* d_ws, size_t ws_size,
                              hipStream_t stream) {
    const float* X = (const float*)d_in[0];  // 8192 x 128
    const float* Z = (const float*)d_in[1];  // 8192 x 32
    float* out = (float*)d_out;
    char* ws = (char*)d_ws;

    __hip_bfloat16* bX = (__hip_bfloat16*)(ws);                 // 2 MB
    __hip_bfloat16* bZ = (__hip_bfloat16*)(ws + 2097152);       // 512 KB
    float* sqX = (float*)(ws + 2621440);                        // 32 KB
    float* sqZ = (float*)(ws + 2654208);                        // 32 KB
    float* pdX = (float*)(ws + 2686976);                        // 4 MB
    float* pdZ = (float*)(ws + 6881280);                        // 4 MB
    float* tX = (float*)(ws + 11075584);                        // 32 KB
    float* tZ = (float*)(ws + 11108352);                        // 32 KB
    int* partial = (int*)(ws + 11141120);                       // 8 KB

    prep_kernel<128><<<N_PTS / 4, 256, 0, stream>>>(X, bX, sqX);
    prep_kernel<32><<<N_PTS / 4, 256, 0, stream>>>(Z, bZ, sqZ);
    thresh_scan<128><<<dim3(N_PTS / IB_BLOCK, JSPLIT), 256, 0, stream>>>(bX, sqX, pdX);
    thresh_scan<32><<<dim3(N_PTS / IB_BLOCK, JSPLIT), 256, 0, stream>>>(bZ, sqZ, pdZ);
    thresh_merge<<<N_PTS / 256, 256, 0, stream>>>(pdX, tX);
    thresh_merge<<<N_PTS / 256, 256, 0, stream>>>(pdZ, tZ);
    count_scan<<<dim3(N_PTS / IB_BLOCK, JSPLIT), 256, 0, stream>>>(bX, sqX, tX, bZ, sqZ, tZ, partial);
    finalize_kernel<<<1, 256, 0, stream>>>(partial, out);
}

// Round 7
// 213.596 us; speedup vs baseline: 1.7810x; 1.7810x over previous
//
#include <hip/hip_runtime.h>
#include <hip/hip_bf16.h>
#include <math.h>

#define N_PTS 8192
#define KNN 8
#define JSPLIT 16
#define WAVES 4
#define IB_BLOCK (WAVES * 16)            // 64 query rows per block
#define JCHUNK (N_PTS / JSPLIT)          // 512 candidates per (wave, js)
#define JTILES (JCHUNK / 16)             // 32 candidate tiles per js
#define NTILE (N_PTS / 16)               // 512 row tiles
#define NPART ((N_PTS / IB_BLOCK) * JSPLIT)  // 2048 count partials

typedef __attribute__((ext_vector_type(8))) short bf16x8;
typedef __attribute__((ext_vector_type(4))) float f32x4;

__device__ __forceinline__ float med3(float a, float b, float c) {
    return __builtin_amdgcn_fmed3f(a, b, c);
}

// Branchless insert of v into ascending sorted d[0..7], dropping the largest.
__device__ __forceinline__ void insertv(float v, float (&d)[8]) {
    float p = d[0];
    d[0] = fminf(v, d[0]);
#pragma unroll
    for (int k = 1; k < 8; ++k) {
        float q = d[k];
        d[k] = med3(v, p, q);
        p = q;
    }
}

// Exact fp32 row-norms (one wave per row, coalesced).
template <int D>
__global__ __launch_bounds__(256) void prep_sq(const float* __restrict__ x,
                                               float* __restrict__ sq) {
    const int row = (blockIdx.x * 256 + threadIdx.x) >> 6;
    const int lane = threadIdx.x & 63;
    float s = 0.f;
    if constexpr (D == 128) {
        float2 v = *reinterpret_cast<const float2*>(x + (size_t)row * D + lane * 2);
        s = fmaf(v.x, v.x, v.y * v.y);
    } else {
        float v = (lane < D) ? x[(size_t)row * D + lane] : 0.f;
        s = v * v;
    }
#pragma unroll
    for (int o = 32; o > 0; o >>= 1) s += __shfl_down(s, o);
    if (lane == 0) sq[row] = s;
}

// Pack into MFMA fragment order: chunk = (tile*KB + kb), lane l holds
// row tile*16+(l&15), cols kb*32+(l>>4)*8 .. +8 as bf16x8. One thread per
// 16B output chunk -> all scan-kernel loads become contiguous 1KB/wave.
template <int D>
__global__ __launch_bounds__(256) void pack_kernel(const float* __restrict__ x,
                                                   bf16x8* __restrict__ pk) {
    constexpr int KB = D / 32;
    const int gid = blockIdx.x * 256 + threadIdx.x;   // < NTILE*KB*64
    const int l = gid & 63;
    const int kb = (gid >> 6) % KB;
    const int tile = gid / (64 * KB);
    const float* src = x + (size_t)(tile * 16 + (l & 15)) * D + kb * 32 + (l >> 4) * 8;
    bf16x8 v;
#pragma unroll
    for (int e = 0; e < 8; ++e) {
        __hip_bfloat16 h = __float2bfloat16(src[e]);
        v[e] = *reinterpret_cast<short*>(&h);
    }
    pk[gid] = v;
}

// Phase 1: value-only top-8 scan over packed fragments.
// C layout (16x16x32 bf16): col = lane&15 (query), row = (lane>>4)*4 + reg (cand).
template <int D>
__global__ __launch_bounds__(256, 4) void thresh_scan(const bf16x8* __restrict__ pk,
                                                      const float* __restrict__ sq,
                                                      float* __restrict__ pd) {
    constexpr int KB = D / 32;
    const int lane = threadIdx.x & 63;
    const int w = __builtin_amdgcn_readfirstlane((int)(threadIdx.x >> 6));
    const int qt = blockIdx.x * WAVES + w;     // query tile index
    const int js = blockIdx.y;
    const int t0 = js * JTILES;
    const int lrow = lane & 15;
    const int jr = (lane >> 4) * 4;

    bf16x8 bfrag[KB];
#pragma unroll
    for (int kb = 0; kb < KB; ++kb) bfrag[kb] = pk[(qt * KB + kb) * 64 + lane];

    float d8[8];
#pragma unroll
    for (int k = 0; k < 8; ++k) d8[k] = __builtin_inff();

#pragma unroll 2
    for (int tt = t0; tt < t0 + JTILES; ++tt) {
        f32x4 acc = {0.f, 0.f, 0.f, 0.f};
#pragma unroll
        for (int kb = 0; kb < KB; ++kb) {
            bf16x8 afrag = pk[(tt * KB + kb) * 64 + lane];
            acc = __builtin_amdgcn_mfma_f32_16x16x32_bf16(afrag, bfrag[kb], acc, 0, 0, 0);
        }
        // dist(j,i) = sq[j] - 2*dot (sq[i] dropped: row-constant, order-safe)
        f32x4 sq4 = *reinterpret_cast<const f32x4*>(sq + tt * 16 + jr);
        if (tt == qt) {  // diagonal tile: mask self (wave-uniform branch)
#pragma unroll
            for (int r = 0; r < 4; ++r) {
                float dist = fmaf(-2.f, acc[r], sq4[r]);
                if (jr + r == lrow) dist = __builtin_inff();
                insertv(dist, d8);
            }
        } else {
#pragma unroll
            for (int r = 0; r < 4; ++r) insertv(fmaf(-2.f, acc[r], sq4[r]), d8);
        }
    }

    // Merge the 4 lanes holding each column: lanes {i, i+16, i+32, i+48}.
    __shared__ float lds_d[WAVES][64][8];
#pragma unroll
    for (int k = 0; k < 8; ++k) lds_d[w][lane][k] = d8[k];
    __syncthreads();
    if (lane < 16) {
        float e[8];
#pragma unroll
        for (int k = 0; k < 8; ++k) e[k] = lds_d[w][lane][k];
#pragma unroll
        for (int p = 1; p < 4; ++p)
#pragma unroll
            for (int k = 0; k < 8; ++k) insertv(lds_d[w][p * 16 + lane][k], e);
        const size_t o = ((size_t)(qt * 16 + lane) * JSPLIT + js) * 8;
#pragma unroll
        for (int k = 0; k < 8; ++k) pd[o + k] = e[k];
    }
}

// Merge JSPLIT partial value-lists per row -> threshold t(row) = 8th smallest.
__global__ __launch_bounds__(256) void thresh_merge(const float* __restrict__ pd,
                                                    float* __restrict__ t) {
    const int row = blockIdx.x * 256 + threadIdx.x;
    const f32x4* p = reinterpret_cast<const f32x4*>(pd + (size_t)row * (JSPLIT * 8));
    float d8[8];
#pragma unroll
    for (int k = 0; k < 8; ++k) d8[k] = __builtin_inff();
    for (int l = 0; l < JSPLIT * 2; ++l) {
        f32x4 v = p[l];
        insertv(v[0], d8); insertv(v[1], d8); insertv(v[2], d8); insertv(v[3], d8);
    }
    t[row] = d8[7];
}

// Phase 2: recompute distances (identical MFMA path on identical packed data)
// for X and Z jointly; count pairs below both row-thresholds.
__global__ __launch_bounds__(256, 4) void count_scan(const bf16x8* __restrict__ pkX,
                                                     const float* __restrict__ sqX,
                                                     const float* __restrict__ tX,
                                                     const bf16x8* __restrict__ pkZ,
                                                     const float* __restrict__ sqZ,
                                                     const float* __restrict__ tZ,
                                                     int* __restrict__ partial) {
    const int lane = threadIdx.x & 63;
    const int w = __builtin_amdgcn_readfirstlane((int)(threadIdx.x >> 6));
    const int qt = blockIdx.x * WAVES + w;
    const int js = blockIdx.y;
    const int t0 = js * JTILES;
    const int lrow = lane & 15;
    const int jr = (lane >> 4) * 4;

    bf16x8 bfX[4];
#pragma unroll
    for (int kb = 0; kb < 4; ++kb) bfX[kb] = pkX[(qt * 4 + kb) * 64 + lane];
    bf16x8 bfZ = pkZ[qt * 64 + lane];
    const float tx = tX[qt * 16 + lrow];
    const float tz = tZ[qt * 16 + lrow];

    int c = 0;
#pragma unroll 2
    for (int tt = t0; tt < t0 + JTILES; ++tt) {
        f32x4 accX = {0.f, 0.f, 0.f, 0.f};
#pragma unroll
        for (int kb = 0; kb < 4; ++kb) {
            bf16x8 af = pkX[(tt * 4 + kb) * 64 + lane];
            accX = __builtin_amdgcn_mfma_f32_16x16x32_bf16(af, bfX[kb], accX, 0, 0, 0);
        }
        f32x4 accZ = {0.f, 0.f, 0.f, 0.f};
        {
            bf16x8 af = pkZ[tt * 64 + lane];
            accZ = __builtin_amdgcn_mfma_f32_16x16x32_bf16(af, bfZ, accZ, 0, 0, 0);
        }
        f32x4 sx4 = *reinterpret_cast<const f32x4*>(sqX + tt * 16 + jr);
        f32x4 sz4 = *reinterpret_cast<const f32x4*>(sqZ + tt * 16 + jr);
        if (tt == qt) {  // diagonal tile: exclude j == i
#pragma unroll
            for (int r = 0; r < 4; ++r) {
                float dx = fmaf(-2.f, accX[r], sx4[r]);
                float dz = fmaf(-2.f, accZ[r], sz4[r]);
                c += (dx <= tx && dz <= tz && (jr + r != lrow)) ? 1 : 0;
            }
        } else {
#pragma unroll
            for (int r = 0; r < 4; ++r) {
                float dx = fmaf(-2.f, accX[r], sx4[r]);
                float dz = fmaf(-2.f, accZ[r], sz4[r]);
                c += (dx <= tx && dz <= tz) ? 1 : 0;
            }
        }
    }

#pragma unroll
    for (int o = 32; o > 0; o >>= 1) c += __shfl_down(c, o);
    __shared__ int wsum[WAVES];
    if (lane == 0) wsum[w] = c;
    __syncthreads();
    if (threadIdx.x == 0)
        partial[blockIdx.y * (N_PTS / IB_BLOCK) + blockIdx.x] = wsum[0] + wsum[1] + wsum[2] + wsum[3];
}

__global__ void finalize_kernel(const int* __restrict__ partial, float* __restrict__ out) {
    int v = 0;
    for (int k = threadIdx.x; k < NPART; k += 256) v += partial[k];
#pragma unroll
    for (int o = 32; o > 0; o >>= 1) v += __shfl_down(v, o);
    __shared__ int wsum[4];
    if ((threadIdx.x & 63) == 0) wsum[threadIdx.x >> 6] = v;
    __syncthreads();
    if (threadIdx.x == 0) {
        // loss = 100 * (2*K*N - 2*matches) / N^2  (exact in double)
        double m = (double)(wsum[0] + wsum[1] + wsum[2] + wsum[3]);
        out[0] = (float)((2.0 * KNN * N_PTS - 2.0 * m) * 100.0 / ((double)N_PTS * (double)N_PTS));
    }
}

extern "C" void kernel_launch(void* const* d_in, const int* in_sizes, int n_in,
                              void* d_out, int out_size, void* d_ws, size_t ws_size,
                              hipStream_t stream) {
    const float* X = (const float*)d_in[0];  // 8192 x 128
    const float* Z = (const float*)d_in[1];  // 8192 x 32
    float* out = (float*)d_out;
    char* ws = (char*)d_ws;

    bf16x8* pkX = (bf16x8*)(ws);                                // 2 MB   (512*4*64*16)
    bf16x8* pkZ = (bf16x8*)(ws + 2097152);                      // 512 KB (512*1*64*16)
    float* sqX = (float*)(ws + 2621440);                        // 32 KB
    float* sqZ = (float*)(ws + 2654208);                        // 32 KB
    float* pdX = (float*)(ws + 2686976);                        // 4 MB
    float* pdZ = (float*)(ws + 6881280);                        // 4 MB
    float* tX = (float*)(ws + 11075584);                        // 32 KB
    float* tZ = (float*)(ws + 11108352);                        // 32 KB
    int* partial = (int*)(ws + 11141120);                       // 8 KB

    prep_sq<128><<<N_PTS / 4, 256, 0, stream>>>(X, sqX);
    prep_sq<32><<<N_PTS / 4, 256, 0, stream>>>(Z, sqZ);
    pack_kernel<128><<<NTILE * 4 * 64 / 256, 256, 0, stream>>>(X, pkX);
    pack_kernel<32><<<NTILE * 1 * 64 / 256, 256, 0, stream>>>(Z, pkZ);
    thresh_scan<128><<<dim3(NTILE / WAVES, JSPLIT), 256, 0, stream>>>(pkX, sqX, pdX);
    thresh_scan<32><<<dim3(NTILE / WAVES, JSPLIT), 256, 0, stream>>>(pkZ, sqZ, pdZ);
    thresh_merge<<<N_PTS / 256, 256, 0, stream>>>(pdX, tX);
    thresh_merge<<<N_PTS / 256, 256, 0, stream>>>(pdZ, tZ);
    count_scan<<<dim3(NTILE / WAVES, JSPLIT), 256, 0, stream>>>(pkX, sqX, tX, pkZ, sqZ, tZ, partial);
    finalize_kernel<<<1, 256, 0, stream>>>(partial, out);
}

// Round 8
// 185.766 us; speedup vs baseline: 2.0479x; 1.1498x over previous
//
#include <hip/hip_runtime.h>
#include <hip/hip_bf16.h>
#include <math.h>

#define N_PTS 8192
#define KNN 8
#define JSPLIT 32
#define WAVES 4
#define NQ 4                              // query tiles resident per wave
#define QT_PER_BLOCK (WAVES * NQ)         // 16 tiles = 256 query rows per block
#define JCHUNK (N_PTS / JSPLIT)           // 256 candidates per (wave, js)
#define JTILES (JCHUNK / 16)              // 16 candidate tiles per js
#define NTILE (N_PTS / 16)                // 512 row tiles
#define NBX (NTILE / QT_PER_BLOCK)        // 32 blocks in x
#define NPART (NBX * JSPLIT)              // 1024 count partials

typedef __attribute__((ext_vector_type(8))) short bf16x8;
typedef __attribute__((ext_vector_type(4))) float f32x4;

__device__ __forceinline__ float med3(float a, float b, float c) {
    return __builtin_amdgcn_fmed3f(a, b, c);
}

// Branchless insert of v into ascending sorted d[0..7], dropping the largest.
__device__ __forceinline__ void insertv(float v, float (&d)[8]) {
    float p = d[0];
    d[0] = fminf(v, d[0]);
#pragma unroll
    for (int k = 1; k < 8; ++k) {
        float q = d[k];
        d[k] = med3(v, p, q);
        p = q;
    }
}

// Exact fp32 row-norms (one wave per row, coalesced).
template <int D>
__global__ __launch_bounds__(256) void prep_sq(const float* __restrict__ x,
                                               float* __restrict__ sq) {
    const int row = (blockIdx.x * 256 + threadIdx.x) >> 6;
    const int lane = threadIdx.x & 63;
    float s = 0.f;
    if constexpr (D == 128) {
        float2 v = *reinterpret_cast<const float2*>(x + (size_t)row * D + lane * 2);
        s = fmaf(v.x, v.x, v.y * v.y);
    } else {
        float v = (lane < D) ? x[(size_t)row * D + lane] : 0.f;
        s = v * v;
    }
#pragma unroll
    for (int o = 32; o > 0; o >>= 1) s += __shfl_down(s, o);
    if (lane == 0) sq[row] = s;
}

// Pack into MFMA fragment order: chunk = (tile*KB + kb), lane l holds
// row tile*16+(l&15), cols kb*32+(l>>4)*8 .. +8 as bf16x8.
template <int D>
__global__ __launch_bounds__(256) void pack_kernel(const float* __restrict__ x,
                                                   bf16x8* __restrict__ pk) {
    constexpr int KB = D / 32;
    const int gid = blockIdx.x * 256 + threadIdx.x;   // < NTILE*KB*64
    const int l = gid & 63;
    const int kb = (gid >> 6) % KB;
    const int tile = gid / (64 * KB);
    const float* src = x + (size_t)(tile * 16 + (l & 15)) * D + kb * 32 + (l >> 4) * 8;
    bf16x8 v;
#pragma unroll
    for (int e = 0; e < 8; ++e) {
        __hip_bfloat16 h = __float2bfloat16(src[e]);
        v[e] = *reinterpret_cast<short*>(&h);
    }
    pk[gid] = v;
}

// Phase 1: value-only top-8 scan. Each wave holds NQ query tiles resident;
// every candidate fragment load feeds NQ MFMAs (4x less L2 traffic).
// C layout (16x16x32 bf16): col = lane&15 (query), row = (lane>>4)*4 + reg (cand).
template <int D>
__global__ __launch_bounds__(256, 3) void thresh_scan(const bf16x8* __restrict__ pk,
                                                      const float* __restrict__ sq,
                                                      float* __restrict__ pd) {
    constexpr int KB = D / 32;
    const int lane = threadIdx.x & 63;
    const int w = __builtin_amdgcn_readfirstlane((int)(threadIdx.x >> 6));
    const int qt0 = blockIdx.x * QT_PER_BLOCK + w * NQ;
    const int js = blockIdx.y;
    const int t0 = js * JTILES;
    const int lrow = lane & 15;
    const int jr = (lane >> 4) * 4;

    bf16x8 bfrag[NQ][KB];
#pragma unroll
    for (int q = 0; q < NQ; ++q)
#pragma unroll
        for (int kb = 0; kb < KB; ++kb)
            bfrag[q][kb] = pk[((size_t)(qt0 + q) * KB + kb) * 64 + lane];

    float d8[NQ][8];
#pragma unroll
    for (int q = 0; q < NQ; ++q)
#pragma unroll
        for (int k = 0; k < 8; ++k) d8[q][k] = __builtin_inff();

#pragma unroll 2
    for (int tt = t0; tt < t0 + JTILES; ++tt) {
        bf16x8 af[KB];
#pragma unroll
        for (int kb = 0; kb < KB; ++kb) af[kb] = pk[((size_t)tt * KB + kb) * 64 + lane];
        f32x4 acc[NQ];
#pragma unroll
        for (int q = 0; q < NQ; ++q) acc[q] = (f32x4){0.f, 0.f, 0.f, 0.f};
#pragma unroll
        for (int kb = 0; kb < KB; ++kb)
#pragma unroll
            for (int q = 0; q < NQ; ++q)
                acc[q] = __builtin_amdgcn_mfma_f32_16x16x32_bf16(af[kb], bfrag[q][kb], acc[q], 0, 0, 0);

        f32x4 sq4 = *reinterpret_cast<const f32x4*>(sq + tt * 16 + jr);
#pragma unroll
        for (int q = 0; q < NQ; ++q) {
            if (tt == qt0 + q) {  // diagonal tile: mask self (wave-uniform)
#pragma unroll
                for (int r = 0; r < 4; ++r) {
                    float dist = fmaf(-2.f, acc[q][r], sq4[r]);
                    if (jr + r == lrow) dist = __builtin_inff();
                    insertv(dist, d8[q]);
                }
            } else {
#pragma unroll
                for (int r = 0; r < 4; ++r) insertv(fmaf(-2.f, acc[q][r], sq4[r]), d8[q]);
            }
        }
    }

    // Merge the 4 lanes holding each column: lanes {i, i+16, i+32, i+48}.
    __shared__ float lds_d[WAVES][NQ][64][8];   // 32 KB
#pragma unroll
    for (int q = 0; q < NQ; ++q)
#pragma unroll
        for (int k = 0; k < 8; ++k) lds_d[w][q][lane][k] = d8[q][k];
    __syncthreads();
    {
        const int t = threadIdx.x;
        const int bq = t >> 4;          // block-level tile index 0..15
        const int col = t & 15;
        const int w2 = bq >> 2;         // bq / NQ
        const int q2 = bq & 3;          // bq % NQ
        float e[8];
#pragma unroll
        for (int k = 0; k < 8; ++k) e[k] = lds_d[w2][q2][col][k];
#pragma unroll
        for (int p = 1; p < 4; ++p)
#pragma unroll
            for (int k = 0; k < 8; ++k) insertv(lds_d[w2][q2][p * 16 + col][k], e);
        const int row = (blockIdx.x * QT_PER_BLOCK + bq) * 16 + col;
        const size_t o = ((size_t)js * N_PTS + row) * 8;
#pragma unroll
        for (int k = 0; k < 8; ++k) pd[o + k] = e[k];
    }
}

// Merge JSPLIT partial value-lists per row -> threshold t(row) = 8th smallest.
// Layout pd[js][row][8] -> coalesced reads per js.
__global__ __launch_bounds__(256) void thresh_merge(const float* __restrict__ pd,
                                                    float* __restrict__ t) {
    const int row = blockIdx.x * 256 + threadIdx.x;
    float d8[8];
#pragma unroll
    for (int k = 0; k < 8; ++k) d8[k] = __builtin_inff();
    for (int js = 0; js < JSPLIT; ++js) {
        const f32x4* p = reinterpret_cast<const f32x4*>(pd + ((size_t)js * N_PTS + row) * 8);
        f32x4 a = p[0], b = p[1];
        insertv(a[0], d8); insertv(a[1], d8); insertv(a[2], d8); insertv(a[3], d8);
        insertv(b[0], d8); insertv(b[1], d8); insertv(b[2], d8); insertv(b[3], d8);
    }
    t[row] = d8[7];
}

// Phase 2: recompute distances (identical MFMA path on identical packed data)
// for X and Z jointly; count pairs below both row-thresholds.
__global__ __launch_bounds__(256, 3) void count_scan(const bf16x8* __restrict__ pkX,
                                                     const float* __restrict__ sqX,
                                                     const float* __restrict__ tX,
                                                     const bf16x8* __restrict__ pkZ,
                                                     const float* __restrict__ sqZ,
                                                     const float* __restrict__ tZ,
                                                     int* __restrict__ partial) {
    const int lane = threadIdx.x & 63;
    const int w = __builtin_amdgcn_readfirstlane((int)(threadIdx.x >> 6));
    const int qt0 = blockIdx.x * QT_PER_BLOCK + w * NQ;
    const int js = blockIdx.y;
    const int t0 = js * JTILES;
    const int lrow = lane & 15;
    const int jr = (lane >> 4) * 4;

    bf16x8 bfX[NQ][4];
    bf16x8 bfZ[NQ];
    float tx[NQ], tz[NQ];
#pragma unroll
    for (int q = 0; q < NQ; ++q) {
#pragma unroll
        for (int kb = 0; kb < 4; ++kb) bfX[q][kb] = pkX[((size_t)(qt0 + q) * 4 + kb) * 64 + lane];
        bfZ[q] = pkZ[(size_t)(qt0 + q) * 64 + lane];
        tx[q] = tX[(qt0 + q) * 16 + lrow];
        tz[q] = tZ[(qt0 + q) * 16 + lrow];
    }

    int c = 0;
#pragma unroll 2
    for (int tt = t0; tt < t0 + JTILES; ++tt) {
        bf16x8 afX[4];
#pragma unroll
        for (int kb = 0; kb < 4; ++kb) afX[kb] = pkX[((size_t)tt * 4 + kb) * 64 + lane];
        bf16x8 afZ = pkZ[(size_t)tt * 64 + lane];

        f32x4 accX[NQ], accZ[NQ];
#pragma unroll
        for (int q = 0; q < NQ; ++q) {
            accX[q] = (f32x4){0.f, 0.f, 0.f, 0.f};
            accZ[q] = (f32x4){0.f, 0.f, 0.f, 0.f};
        }
#pragma unroll
        for (int kb = 0; kb < 4; ++kb)
#pragma unroll
            for (int q = 0; q < NQ; ++q)
                accX[q] = __builtin_amdgcn_mfma_f32_16x16x32_bf16(afX[kb], bfX[q][kb], accX[q], 0, 0, 0);
#pragma unroll
        for (int q = 0; q < NQ; ++q)
            accZ[q] = __builtin_amdgcn_mfma_f32_16x16x32_bf16(afZ, bfZ[q], accZ[q], 0, 0, 0);

        f32x4 sx4 = *reinterpret_cast<const f32x4*>(sqX + tt * 16 + jr);
        f32x4 sz4 = *reinterpret_cast<const f32x4*>(sqZ + tt * 16 + jr);
#pragma unroll
        for (int q = 0; q < NQ; ++q) {
            if (tt == qt0 + q) {  // diagonal tile: exclude j == i
#pragma unroll
                for (int r = 0; r < 4; ++r) {
                    float dx = fmaf(-2.f, accX[q][r], sx4[r]);
                    float dz = fmaf(-2.f, accZ[q][r], sz4[r]);
                    c += (dx <= tx[q] && dz <= tz[q] && (jr + r != lrow)) ? 1 : 0;
                }
            } else {
#pragma unroll
                for (int r = 0; r < 4; ++r) {
                    float dx = fmaf(-2.f, accX[q][r], sx4[r]);
                    float dz = fmaf(-2.f, accZ[q][r], sz4[r]);
                    c += (dx <= tx[q] && dz <= tz[q]) ? 1 : 0;
                }
            }
        }
    }

#pragma unroll
    for (int o = 32; o > 0; o >>= 1) c += __shfl_down(c, o);
    __shared__ int wsum[WAVES];
    if (lane == 0) wsum[w] = c;
    __syncthreads();
    if (threadIdx.x == 0)
        partial[blockIdx.y * NBX + blockIdx.x] = wsum[0] + wsum[1] + wsum[2] + wsum[3];
}

__global__ void finalize_kernel(const int* __restrict__ partial, float* __restrict__ out) {
    int v = 0;
    for (int k = threadIdx.x; k < NPART; k += 256) v += partial[k];
#pragma unroll
    for (int o = 32; o > 0; o >>= 1) v += __shfl_down(v, o);
    __shared__ int wsum[4];
    if ((threadIdx.x & 63) == 0) wsum[threadIdx.x >> 6] = v;
    __syncthreads();
    if (threadIdx.x == 0) {
        // loss = 100 * (2*K*N - 2*matches) / N^2  (exact in double)
        double m = (double)(wsum[0] + wsum[1] + wsum[2] + wsum[3]);
        out[0] = (float)((2.0 * KNN * N_PTS - 2.0 * m) * 100.0 / ((double)N_PTS * (double)N_PTS));
    }
}

extern "C" void kernel_launch(void* const* d_in, const int* in_sizes, int n_in,
                              void* d_out, int out_size, void* d_ws, size_t ws_size,
                              hipStream_t stream) {
    const float* X = (const float*)d_in[0];  // 8192 x 128
    const float* Z = (const float*)d_in[1];  // 8192 x 32
    float* out = (float*)d_out;
    char* ws = (char*)d_ws;

    bf16x8* pkX = (bf16x8*)(ws);                                // 2 MB
    bf16x8* pkZ = (bf16x8*)(ws + 2097152);                      // 512 KB
    float* sqX = (float*)(ws + 2621440);                        // 32 KB
    float* sqZ = (float*)(ws + 2654208);                        // 32 KB
    float* pdX = (float*)(ws + 2686976);                        // 8 MB (js-major)
    float* pdZ = (float*)(ws + 11075584);                       // 8 MB
    float* tX = (float*)(ws + 19464192);                        // 32 KB
    float* tZ = (float*)(ws + 19496960);                        // 32 KB
    int* partial = (int*)(ws + 19529728);                       // 4 KB

    prep_sq<128><<<N_PTS / 4, 256, 0, stream>>>(X, sqX);
    prep_sq<32><<<N_PTS / 4, 256, 0, stream>>>(Z, sqZ);
    pack_kernel<128><<<NTILE * 4 * 64 / 256, 256, 0, stream>>>(X, pkX);
    pack_kernel<32><<<NTILE * 1 * 64 / 256, 256, 0, stream>>>(Z, pkZ);
    thresh_scan<128><<<dim3(NBX, JSPLIT), 256, 0, stream>>>(pkX, sqX, pdX);
    thresh_scan<32><<<dim3(NBX, JSPLIT), 256, 0, stream>>>(pkZ, sqZ, pdZ);
    thresh_merge<<<N_PTS / 256, 256, 0, stream>>>(pdX, tX);
    thresh_merge<<<N_PTS / 256, 256, 0, stream>>>(pdZ, tZ);
    count_scan<<<dim3(NBX, JSPLIT), 256, 0, stream>>>(pkX, sqX, tX, pkZ, sqZ, tZ, partial);
    finalize_kernel<<<1, 256, 0, stream>>>(partial, out);
}

// Round 9
// 167.442 us; speedup vs baseline: 2.2720x; 1.1094x over previous
//
#include <hip/hip_runtime.h>
#include <hip/hip_bf16.h>
#include <math.h>

#define N_PTS 8192
#define KNN 8
#define JSPLIT 16
#define WAVES 4
#define NQ 2                               // query tiles resident per wave
#define QT_PER_BLOCK (WAVES * NQ)          // 8 tiles = 128 query rows per block
#define NTILE (N_PTS / 16)                 // 512 row tiles
#define NBX (NTILE / QT_PER_BLOCK)         // 64 blocks in x
#define JCHUNK (N_PTS / JSPLIT)            // 512 candidates per block-column
#define JTILES (JCHUNK / 16)               // 32 candidate tiles per js
#define TB 2                               // tiles per LDS stage batch
#define NB (JTILES / TB)                   // 16 batches
#define NPART (NBX * JSPLIT)               // 1024 count partials

typedef __attribute__((ext_vector_type(8))) short bf16x8;
typedef __attribute__((ext_vector_type(4))) float f32x4;

__device__ __forceinline__ float med3(float a, float b, float c) {
    return __builtin_amdgcn_fmed3f(a, b, c);
}

// Branchless insert of v into ascending sorted d[0..7], dropping the largest.
__device__ __forceinline__ void insertv(float v, float (&d)[8]) {
    float p = d[0];
    d[0] = fminf(v, d[0]);
#pragma unroll
    for (int k = 1; k < 8; ++k) {
        float q = d[k];
        d[k] = med3(v, p, q);
        p = q;
    }
}

// Exact fp32 row-norms (one wave per row, coalesced).
template <int D>
__global__ __launch_bounds__(256) void prep_sq(const float* __restrict__ x,
                                               float* __restrict__ sq) {
    const int row = (blockIdx.x * 256 + threadIdx.x) >> 6;
    const int lane = threadIdx.x & 63;
    float s = 0.f;
    if constexpr (D == 128) {
        float2 v = *reinterpret_cast<const float2*>(x + (size_t)row * D + lane * 2);
        s = fmaf(v.x, v.x, v.y * v.y);
    } else {
        float v = (lane < D) ? x[(size_t)row * D + lane] : 0.f;
        s = v * v;
    }
#pragma unroll
    for (int o = 32; o > 0; o >>= 1) s += __shfl_down(s, o);
    if (lane == 0) sq[row] = s;
}

// Pack into MFMA fragment order: chunk = (tile*KB + kb), lane l holds
// row tile*16+(l&15), cols kb*32+(l>>4)*8 .. +8 as bf16x8.
template <int D>
__global__ __launch_bounds__(256) void pack_kernel(const float* __restrict__ x,
                                                   bf16x8* __restrict__ pk) {
    constexpr int KB = D / 32;
    const int gid = blockIdx.x * 256 + threadIdx.x;   // < NTILE*KB*64
    const int l = gid & 63;
    const int kb = (gid >> 6) % KB;
    const int tile = gid / (64 * KB);
    const float* src = x + (size_t)(tile * 16 + (l & 15)) * D + kb * 32 + (l >> 4) * 8;
    bf16x8 v;
#pragma unroll
    for (int e = 0; e < 8; ++e) {
        __hip_bfloat16 h = __float2bfloat16(src[e]);
        v[e] = *reinterpret_cast<short*>(&h);
    }
    pk[gid] = v;
}

// Phase 1: value-only top-8 scan. Candidate tiles staged in double-buffered
// LDS, shared by all 4 waves (4x less global traffic, short ds_read latency).
// C layout (16x16x32 bf16): col = lane&15 (query), row = (lane>>4)*4 + reg (cand).
template <int D>
__global__ __launch_bounds__(256, 4) void thresh_scan(const bf16x8* __restrict__ pk,
                                                      const float* __restrict__ sq,
                                                      float* __restrict__ pd) {
    constexpr int KB = D / 32;
    constexpr int BCH = TB * KB * 64;   // chunks per batch: 512 (D=128) / 128 (D=32)
    __shared__ bf16x8 sbuf[2][BCH];
    __shared__ float lds_d[WAVES][NQ][64][8];

    const int t = threadIdx.x;
    const int lane = t & 63;
    const int w = __builtin_amdgcn_readfirstlane(t >> 6);
    const int qt0 = blockIdx.x * QT_PER_BLOCK + w * NQ;
    const int js = blockIdx.y;
    const int t0 = js * JTILES;
    const int lrow = lane & 15;
    const int jr = (lane >> 4) * 4;

    bf16x8 bfrag[NQ][KB];
#pragma unroll
    for (int q = 0; q < NQ; ++q)
#pragma unroll
        for (int kb = 0; kb < KB; ++kb)
            bfrag[q][kb] = pk[((size_t)(qt0 + q) * KB + kb) * 64 + lane];

    float d8[NQ][8];
#pragma unroll
    for (int q = 0; q < NQ; ++q)
#pragma unroll
        for (int k = 0; k < 8; ++k) d8[q][k] = __builtin_inff();

    // Stage batch 0.
    {
        const size_t gb = (size_t)t0 * KB * 64;
        if constexpr (BCH == 512) {
            sbuf[0][t] = pk[gb + t];
            sbuf[0][t + 256] = pk[gb + t + 256];
        } else {
            if (t < BCH) sbuf[0][t] = pk[gb + t];
        }
    }
    __syncthreads();

    int cur = 0;
    bf16x8 stg0, stg1;
    for (int b = 0; b < NB; ++b) {
        // Issue next-batch global loads early (latency hides under compute).
        if (b + 1 < NB) {
            const size_t gb = (size_t)(t0 + (b + 1) * TB) * KB * 64;
            if constexpr (BCH == 512) {
                stg0 = pk[gb + t];
                stg1 = pk[gb + t + 256];
            } else {
                if (t < BCH) stg0 = pk[gb + t];
            }
        }
        // Consume TB tiles from sbuf[cur].
#pragma unroll
        for (int u = 0; u < TB; ++u) {
            const int tt = t0 + b * TB + u;
            f32x4 acc[NQ];
#pragma unroll
            for (int q = 0; q < NQ; ++q) acc[q] = (f32x4){0.f, 0.f, 0.f, 0.f};
#pragma unroll
            for (int kb = 0; kb < KB; ++kb) {
                bf16x8 af = sbuf[cur][u * KB * 64 + kb * 64 + lane];
#pragma unroll
                for (int q = 0; q < NQ; ++q)
                    acc[q] = __builtin_amdgcn_mfma_f32_16x16x32_bf16(af, bfrag[q][kb], acc[q], 0, 0, 0);
            }
            f32x4 sq4 = *reinterpret_cast<const f32x4*>(sq + tt * 16 + jr);
#pragma unroll
            for (int q = 0; q < NQ; ++q) {
                if (tt == qt0 + q) {  // diagonal tile: mask self (wave-uniform)
#pragma unroll
                    for (int r = 0; r < 4; ++r) {
                        float dist = fmaf(-2.f, acc[q][r], sq4[r]);
                        if (jr + r == lrow) dist = __builtin_inff();
                        insertv(dist, d8[q]);
                    }
                } else {
#pragma unroll
                    for (int r = 0; r < 4; ++r) insertv(fmaf(-2.f, acc[q][r], sq4[r]), d8[q]);
                }
            }
        }
        // Write next batch into the other buffer; one barrier per batch.
        if (b + 1 < NB) {
            if constexpr (BCH == 512) {
                sbuf[cur ^ 1][t] = stg0;
                sbuf[cur ^ 1][t + 256] = stg1;
            } else {
                if (t < BCH) sbuf[cur ^ 1][t] = stg0;
            }
        }
        __syncthreads();
        cur ^= 1;
    }

    // Merge the 4 lanes holding each column: lanes {i, i+16, i+32, i+48}.
#pragma unroll
    for (int q = 0; q < NQ; ++q)
#pragma unroll
        for (int k = 0; k < 8; ++k) lds_d[w][q][lane][k] = d8[q][k];
    __syncthreads();
    if (t < QT_PER_BLOCK * 16) {
        const int bq = t >> 4;          // block-level tile index 0..7
        const int col = t & 15;
        const int w2 = bq >> 1;         // bq / NQ
        const int q2 = bq & 1;          // bq % NQ
        float e[8];
#pragma unroll
        for (int k = 0; k < 8; ++k) e[k] = lds_d[w2][q2][col][k];
#pragma unroll
        for (int p = 1; p < 4; ++p)
#pragma unroll
            for (int k = 0; k < 8; ++k) insertv(lds_d[w2][q2][p * 16 + col][k], e);
        const int row = (blockIdx.x * QT_PER_BLOCK + bq) * 16 + col;
        const size_t o = ((size_t)js * N_PTS + row) * 8;
#pragma unroll
        for (int k = 0; k < 8; ++k) pd[o + k] = e[k];
    }
}

// Merge JSPLIT partial value-lists per row -> threshold t(row) = 8th smallest.
__global__ __launch_bounds__(256) void thresh_merge(const float* __restrict__ pd,
                                                    float* __restrict__ t) {
    const int row = blockIdx.x * 256 + threadIdx.x;
    float d8[8];
#pragma unroll
    for (int k = 0; k < 8; ++k) d8[k] = __builtin_inff();
    for (int js = 0; js < JSPLIT; ++js) {
        const f32x4* p = reinterpret_cast<const f32x4*>(pd + ((size_t)js * N_PTS + row) * 8);
        f32x4 a = p[0], b = p[1];
        insertv(a[0], d8); insertv(a[1], d8); insertv(a[2], d8); insertv(a[3], d8);
        insertv(b[0], d8); insertv(b[1], d8); insertv(b[2], d8); insertv(b[3], d8);
    }
    t[row] = d8[7];
}

// Phase 2: recompute distances (identical MFMA path on identical packed data)
// for X and Z jointly; count pairs below both row-thresholds.
__global__ __launch_bounds__(256, 4) void count_scan(const bf16x8* __restrict__ pkX,
                                                     const float* __restrict__ sqX,
                                                     const float* __restrict__ tX,
                                                     const bf16x8* __restrict__ pkZ,
                                                     const float* __restrict__ sqZ,
                                                     const float* __restrict__ tZ,
                                                     int* __restrict__ partial) {
    __shared__ bf16x8 sbX[2][TB * 4 * 64];   // 16 KB
    __shared__ bf16x8 sbZ[2][TB * 1 * 64];   // 4 KB
    __shared__ int wsum[WAVES];

    const int t = threadIdx.x;
    const int lane = t & 63;
    const int w = __builtin_amdgcn_readfirstlane(t >> 6);
    const int qt0 = blockIdx.x * QT_PER_BLOCK + w * NQ;
    const int js = blockIdx.y;
    const int t0 = js * JTILES;
    const int lrow = lane & 15;
    const int jr = (lane >> 4) * 4;

    bf16x8 bfX[NQ][4];
    bf16x8 bfZ[NQ];
    float tx[NQ], tz[NQ];
#pragma unroll
    for (int q = 0; q < NQ; ++q) {
#pragma unroll
        for (int kb = 0; kb < 4; ++kb) bfX[q][kb] = pkX[((size_t)(qt0 + q) * 4 + kb) * 64 + lane];
        bfZ[q] = pkZ[(size_t)(qt0 + q) * 64 + lane];
        tx[q] = tX[(qt0 + q) * 16 + lrow];
        tz[q] = tZ[(qt0 + q) * 16 + lrow];
    }

    // Stage batch 0.
    {
        const size_t gx = (size_t)t0 * 4 * 64;
        const size_t gz = (size_t)t0 * 64;
        sbX[0][t] = pkX[gx + t];
        sbX[0][t + 256] = pkX[gx + t + 256];
        if (t < TB * 64) sbZ[0][t] = pkZ[gz + t];
    }
    __syncthreads();

    int c = 0;
    int cur = 0;
    bf16x8 sx0, sx1, sz0;
    for (int b = 0; b < NB; ++b) {
        if (b + 1 < NB) {
            const size_t gx = (size_t)(t0 + (b + 1) * TB) * 4 * 64;
            const size_t gz = (size_t)(t0 + (b + 1) * TB) * 64;
            sx0 = pkX[gx + t];
            sx1 = pkX[gx + t + 256];
            if (t < TB * 64) sz0 = pkZ[gz + t];
        }
#pragma unroll
        for (int u = 0; u < TB; ++u) {
            const int tt = t0 + b * TB + u;
            f32x4 accX[NQ], accZ[NQ];
#pragma unroll
            for (int q = 0; q < NQ; ++q) {
                accX[q] = (f32x4){0.f, 0.f, 0.f, 0.f};
                accZ[q] = (f32x4){0.f, 0.f, 0.f, 0.f};
            }
#pragma unroll
            for (int kb = 0; kb < 4; ++kb) {
                bf16x8 af = sbX[cur][u * 4 * 64 + kb * 64 + lane];
#pragma unroll
                for (int q = 0; q < NQ; ++q)
                    accX[q] = __builtin_amdgcn_mfma_f32_16x16x32_bf16(af, bfX[q][kb], accX[q], 0, 0, 0);
            }
            {
                bf16x8 afZ = sbZ[cur][u * 64 + lane];
#pragma unroll
                for (int q = 0; q < NQ; ++q)
                    accZ[q] = __builtin_amdgcn_mfma_f32_16x16x32_bf16(afZ, bfZ[q], accZ[q], 0, 0, 0);
            }
            f32x4 sx4 = *reinterpret_cast<const f32x4*>(sqX + tt * 16 + jr);
            f32x4 sz4 = *reinterpret_cast<const f32x4*>(sqZ + tt * 16 + jr);
#pragma unroll
            for (int q = 0; q < NQ; ++q) {
                if (tt == qt0 + q) {  // diagonal tile: exclude j == i
#pragma unroll
                    for (int r = 0; r < 4; ++r) {
                        float dx = fmaf(-2.f, accX[q][r], sx4[r]);
                        float dz = fmaf(-2.f, accZ[q][r], sz4[r]);
                        c += (dx <= tx[q] && dz <= tz[q] && (jr + r != lrow)) ? 1 : 0;
                    }
                } else {
#pragma unroll
                    for (int r = 0; r < 4; ++r) {
                        float dx = fmaf(-2.f, accX[q][r], sx4[r]);
                        float dz = fmaf(-2.f, accZ[q][r], sz4[r]);
                        c += (dx <= tx[q] && dz <= tz[q]) ? 1 : 0;
                    }
                }
            }
        }
        if (b + 1 < NB) {
            sbX[cur ^ 1][t] = sx0;
            sbX[cur ^ 1][t + 256] = sx1;
            if (t < TB * 64) sbZ[cur ^ 1][t] = sz0;
        }
        __syncthreads();
        cur ^= 1;
    }

#pragma unroll
    for (int o = 32; o > 0; o >>= 1) c += __shfl_down(c, o);
    if (lane == 0) wsum[w] = c;
    __syncthreads();
    if (t == 0)
        partial[blockIdx.y * NBX + blockIdx.x] = wsum[0] + wsum[1] + wsum[2] + wsum[3];
}

__global__ void finalize_kernel(const int* __restrict__ partial, float* __restrict__ out) {
    int v = 0;
    for (int k = threadIdx.x; k < NPART; k += 256) v += partial[k];
#pragma unroll
    for (int o = 32; o > 0; o >>= 1) v += __shfl_down(v, o);
    __shared__ int wsum[4];
    if ((threadIdx.x & 63) == 0) wsum[threadIdx.x >> 6] = v;
    __syncthreads();
    if (threadIdx.x == 0) {
        // loss = 100 * (2*K*N - 2*matches) / N^2  (exact in double)
        double m = (double)(wsum[0] + wsum[1] + wsum[2] + wsum[3]);
        out[0] = (float)((2.0 * KNN * N_PTS - 2.0 * m) * 100.0 / ((double)N_PTS * (double)N_PTS));
    }
}

extern "C" void kernel_launch(void* const* d_in, const int* in_sizes, int n_in,
                              void* d_out, int out_size, void* d_ws, size_t ws_size,
                              hipStream_t stream) {
    const float* X = (const float*)d_in[0];  // 8192 x 128
    const float* Z = (const float*)d_in[1];  // 8192 x 32
    float* out = (float*)d_out;
    char* ws = (char*)d_ws;

    bf16x8* pkX = (bf16x8*)(ws);                                // 2 MB
    bf16x8* pkZ = (bf16x8*)(ws + 2097152);                      // 512 KB
    float* sqX = (float*)(ws + 2621440);                        // 32 KB
    float* sqZ = (float*)(ws + 2654208);                        // 32 KB
    float* pdX = (float*)(ws + 2686976);                        // 4 MB (js-major)
    float* pdZ = (float*)(ws + 11075584);                       // 4 MB
    float* tX = (float*)(ws + 19464192);                        // 32 KB
    float* tZ = (float*)(ws + 19496960);                        // 32 KB
    int* partial = (int*)(ws + 19529728);                       // 4 KB

    prep_sq<128><<<N_PTS / 4, 256, 0, stream>>>(X, sqX);
    prep_sq<32><<<N_PTS / 4, 256, 0, stream>>>(Z, sqZ);
    pack_kernel<128><<<NTILE * 4 * 64 / 256, 256, 0, stream>>>(X, pkX);
    pack_kernel<32><<<NTILE * 1 * 64 / 256, 256, 0, stream>>>(Z, pkZ);
    thresh_scan<128><<<dim3(NBX, JSPLIT), 256, 0, stream>>>(pkX, sqX, pdX);
    thresh_scan<32><<<dim3(NBX, JSPLIT), 256, 0, stream>>>(pkZ, sqZ, pdZ);
    thresh_merge<<<N_PTS / 256, 256, 0, stream>>>(pdX, tX);
    thresh_merge<<<N_PTS / 256, 256, 0, stream>>>(pdZ, tZ);
    count_scan<<<dim3(NBX, JSPLIT), 256, 0, stream>>>(pkX, sqX, tX, pkZ, sqZ, tZ, partial);
    finalize_kernel<<<1, 256, 0, stream>>>(partial, out);
}

// Round 13
// 156.784 us; speedup vs baseline: 2.4264x; 1.0680x over previous
//
#include <hip/hip_runtime.h>
#include <hip/hip_bf16.h>
#include <math.h>

#define N_PTS 8192
#define KNN 8
#define JSPLIT 16
#define WAVES 4
#define NQ 2                               // query tiles resident per wave
#define QT_PER_BLOCK (WAVES * NQ)          // 8 tiles = 128 query rows per block
#define NTILE (N_PTS / 16)                 // 512 row tiles
#define NBX (NTILE / QT_PER_BLOCK)         // 64 blocks in x
#define JTILES ((N_PTS / JSPLIT) / 16)     // 32 candidate tiles per js
#define TB 4                               // tiles per LDS stage batch
#define NB (JTILES / TB)                   // 8 batches
#define NPART (NBX * JSPLIT)               // 1024 count partials

typedef __attribute__((ext_vector_type(8))) short bf16x8;
typedef __attribute__((ext_vector_type(4))) float f32x4;

__device__ __forceinline__ float med3(float a, float b, float c) {
    return __builtin_amdgcn_fmed3f(a, b, c);
}

// Branchless insert of v into ascending sorted d[0..7], dropping the largest.
__device__ __forceinline__ void insertv(float v, float (&d)[8]) {
    float p = d[0];
    d[0] = fminf(v, d[0]);
#pragma unroll
    for (int k = 1; k < 8; ++k) {
        float q = d[k];
        d[k] = med3(v, p, q);
        p = q;
    }
}

// Exact fp32 row-norms (one wave per row, coalesced).
template <int D>
__global__ __launch_bounds__(256) void prep_sq(const float* __restrict__ x,
                                               float* __restrict__ sq) {
    const int row = (blockIdx.x * 256 + threadIdx.x) >> 6;
    const int lane = threadIdx.x & 63;
    float s = 0.f;
    if constexpr (D == 128) {
        float2 v = *reinterpret_cast<const float2*>(x + (size_t)row * D + lane * 2);
        s = fmaf(v.x, v.x, v.y * v.y);
    } else {
        float v = (lane < D) ? x[(size_t)row * D + lane] : 0.f;
        s = v * v;
    }
#pragma unroll
    for (int o = 32; o > 0; o >>= 1) s += __shfl_down(s, o);
    if (lane == 0) sq[row] = s;
}

// Pack into MFMA fragment order via LDS transpose.
// Reads coalesced float4; writes coalesced 16B fragment chunks.
// Fragment chunk (tile*KB+kb)*64 + l holds row tile*16+(l&15),
// cols kb*32+(l>>4)*8..+8 as bf16x8.
template <int D>
__global__ __launch_bounds__(256) void pack_kernel(const float* __restrict__ x,
                                                   bf16x8* __restrict__ pk) {
    constexpr int KB = D / 32;
    constexpr int TPB = 2048 / (16 * D);   // tiles per block: 1 (D=128), 4 (D=32)
    constexpr int PAD = 8;                 // bf16 pad per row (bank spread)
    __shared__ short lds[16 * TPB * (D + PAD)];
    const int t = threadIdx.x;
    const size_t base = (size_t)blockIdx.x * 2048;
#pragma unroll
    for (int h = 0; h < 2; ++h) {
        const int fi = (t * 2 + h) * 4;          // flat float idx in block
        float4 v = *reinterpret_cast<const float4*>(x + base + fi);
        const int row = fi / D;
        const int col = fi % D;
        short4 s;
        __hip_bfloat16 b0 = __float2bfloat16(v.x);
        __hip_bfloat16 b1 = __float2bfloat16(v.y);
        __hip_bfloat16 b2 = __float2bfloat16(v.z);
        __hip_bfloat16 b3 = __float2bfloat16(v.w);
        s.x = *reinterpret_cast<short*>(&b0);
        s.y = *reinterpret_cast<short*>(&b1);
        s.z = *reinterpret_cast<short*>(&b2);
        s.w = *reinterpret_cast<short*>(&b3);
        *reinterpret_cast<short4*>(&lds[row * (D + PAD) + col]) = s;
    }
    __syncthreads();
    const int tpb_idx = t / (KB * 64);
    const int rem = t % (KB * 64);
    const int kb = rem >> 6, l = rem & 63;
    const int row = tpb_idx * 16 + (l & 15);
    const int col = kb * 32 + (l >> 4) * 8;
    bf16x8 v = *reinterpret_cast<const bf16x8*>(&lds[row * (D + PAD) + col]);
    const int tile = blockIdx.x * TPB + tpb_idx;
    pk[(size_t)(tile * KB + kb) * 64 + l] = v;
}

// Phase 1 (fused X+Z): value-only top-8 scan. Candidate tiles double-buffered
// in LDS, shared by all 4 waves. C layout (16x16x32 bf16):
// col = lane&15 (query), row = (lane>>4)*4 + reg (cand).
__global__ __launch_bounds__(256, 3) void thresh_scan_xz(const bf16x8* __restrict__ pkX,
                                                         const float* __restrict__ sqX,
                                                         float* __restrict__ pdX,
                                                         const bf16x8* __restrict__ pkZ,
                                                         const float* __restrict__ sqZ,
                                                         float* __restrict__ pdZ) {
    __shared__ char smem[40960];
    bf16x8(*sbX)[TB * 4 * 64] = reinterpret_cast<bf16x8(*)[TB * 4 * 64]>(smem);          // 2x16KB
    bf16x8(*sbZ)[TB * 64] = reinterpret_cast<bf16x8(*)[TB * 64]>(smem + 32768);          // 2x4KB

    const int t = threadIdx.x;
    const int lane = t & 63;
    const int w = __builtin_amdgcn_readfirstlane(t >> 6);
    const int qt0 = blockIdx.x * QT_PER_BLOCK + w * NQ;
    const int js = blockIdx.y;
    const int t0 = js * JTILES;
    const int lrow = lane & 15;
    const int jr = (lane >> 4) * 4;

    bf16x8 bfX[NQ][4];
    bf16x8 bfZ[NQ];
#pragma unroll
    for (int q = 0; q < NQ; ++q) {
#pragma unroll
        for (int kb = 0; kb < 4; ++kb) bfX[q][kb] = pkX[((size_t)(qt0 + q) * 4 + kb) * 64 + lane];
        bfZ[q] = pkZ[(size_t)(qt0 + q) * 64 + lane];
    }

    float d8x[NQ][8], d8z[NQ][8];
#pragma unroll
    for (int q = 0; q < NQ; ++q)
#pragma unroll
        for (int k = 0; k < 8; ++k) { d8x[q][k] = __builtin_inff(); d8z[q][k] = __builtin_inff(); }

    // Stage batch 0: X 1024 chunks (4/thread), Z 256 chunks (1/thread).
    {
        const size_t gx = (size_t)t0 * 4 * 64;
        const size_t gz = (size_t)t0 * 64;
#pragma unroll
        for (int s = 0; s < 4; ++s) sbX[0][t + s * 256] = pkX[gx + t + s * 256];
        sbZ[0][t] = pkZ[gz + t];
    }
    __syncthreads();

    int cur = 0;
    bf16x8 rx[4], rz;
    for (int b = 0; b < NB; ++b) {
        if (b + 1 < NB) {  // issue next-batch loads early
            const size_t gx = (size_t)(t0 + (b + 1) * TB) * 4 * 64;
            const size_t gz = (size_t)(t0 + (b + 1) * TB) * 64;
#pragma unroll
            for (int s = 0; s < 4; ++s) rx[s] = pkX[gx + t + s * 256];
            rz = pkZ[gz + t];
        }
#pragma unroll
        for (int u = 0; u < TB; ++u) {
            const int tt = t0 + b * TB + u;
            f32x4 accX[NQ], accZ[NQ];
#pragma unroll
            for (int q = 0; q < NQ; ++q) {
                accX[q] = (f32x4){0.f, 0.f, 0.f, 0.f};
                accZ[q] = (f32x4){0.f, 0.f, 0.f, 0.f};
            }
#pragma unroll
            for (int kb = 0; kb < 4; ++kb) {
                bf16x8 af = sbX[cur][u * 256 + kb * 64 + lane];
#pragma unroll
                for (int q = 0; q < NQ; ++q)
                    accX[q] = __builtin_amdgcn_mfma_f32_16x16x32_bf16(af, bfX[q][kb], accX[q], 0, 0, 0);
            }
            {
                bf16x8 afZ = sbZ[cur][u * 64 + lane];
#pragma unroll
                for (int q = 0; q < NQ; ++q)
                    accZ[q] = __builtin_amdgcn_mfma_f32_16x16x32_bf16(afZ, bfZ[q], accZ[q], 0, 0, 0);
            }
            f32x4 sx4 = *reinterpret_cast<const f32x4*>(sqX + tt * 16 + jr);
            f32x4 sz4 = *reinterpret_cast<const f32x4*>(sqZ + tt * 16 + jr);
#pragma unroll
            for (int q = 0; q < NQ; ++q) {
                if (tt == qt0 + q) {  // diagonal tile: mask self (wave-uniform)
#pragma unroll
                    for (int r = 0; r < 4; ++r) {
                        float dx = fmaf(-2.f, accX[q][r], sx4[r]);
                        float dz = fmaf(-2.f, accZ[q][r], sz4[r]);
                        if (jr + r == lrow) { dx = __builtin_inff(); dz = __builtin_inff(); }
                        insertv(dx, d8x[q]);
                        insertv(dz, d8z[q]);
                    }
                } else {
#pragma unroll
                    for (int r = 0; r < 4; ++r) {
                        insertv(fmaf(-2.f, accX[q][r], sx4[r]), d8x[q]);
                        insertv(fmaf(-2.f, accZ[q][r], sz4[r]), d8z[q]);
                    }
                }
            }
        }
        if (b + 1 < NB) {
#pragma unroll
            for (int s = 0; s < 4; ++s) sbX[cur ^ 1][t + s * 256] = rx[s];
            sbZ[cur ^ 1][t] = rz;
        }
        __syncthreads();
        cur ^= 1;
    }

    // Merge 4 lanes per column; LDS aliased over the (now-dead) stage buffers.
    float(*ldsx)[NQ][64][8] = reinterpret_cast<float(*)[NQ][64][8]>(smem);            // 16KB
    float(*ldsz)[NQ][64][8] = reinterpret_cast<float(*)[NQ][64][8]>(smem + 16384);    // 16KB
#pragma unroll
    for (int q = 0; q < NQ; ++q)
#pragma unroll
        for (int k = 0; k < 8; ++k) { ldsx[w][q][lane][k] = d8x[q][k]; ldsz[w][q][lane][k] = d8z[q][k]; }
    __syncthreads();
    {
        const int half = t >> 7;          // 0: X rows, 1: Z rows
        const int u = t & 127;
        const int bq = u >> 4;            // block-level tile 0..7
        const int col = u & 15;
        const int w2 = bq >> 1, q2 = bq & 1;
        const float(*src)[NQ][64][8] = half ? ldsz : ldsx;
        float e[8];
#pragma unroll
        for (int k = 0; k < 8; ++k) e[k] = src[w2][q2][col][k];
#pragma unroll
        for (int p = 1; p < 4; ++p)
#pragma unroll
            for (int k = 0; k < 8; ++k) insertv(src[w2][q2][p * 16 + col][k], e);
        const int row = (blockIdx.x * QT_PER_BLOCK + bq) * 16 + col;
        float* pd = half ? pdZ : pdX;
        const size_t o = ((size_t)js * N_PTS + row) * 8;
#pragma unroll
        for (int k = 0; k < 8; ++k) pd[o + k] = e[k];
    }
}

// Merge JSPLIT partial value-lists per row -> threshold t(row) = 8th smallest.
// blockIdx.y: 0 = X, 1 = Z.
__global__ __launch_bounds__(256) void thresh_merge(const float* __restrict__ pdX,
                                                    float* __restrict__ tXo,
                                                    const float* __restrict__ pdZ,
                                                    float* __restrict__ tZo) {
    const int row = blockIdx.x * 256 + threadIdx.x;
    const float* pd = blockIdx.y ? pdZ : pdX;
    float* to = blockIdx.y ? tZo : tXo;
    float d8[8];
#pragma unroll
    for (int k = 0; k < 8; ++k) d8[k] = __builtin_inff();
    for (int js = 0; js < JSPLIT; ++js) {
        const f32x4* p = reinterpret_cast<const f32x4*>(pd + ((size_t)js * N_PTS + row) * 8);
        f32x4 a = p[0], b = p[1];
        insertv(a[0], d8); insertv(a[1], d8); insertv(a[2], d8); insertv(a[3], d8);
        insertv(b[0], d8); insertv(b[1], d8); insertv(b[2], d8); insertv(b[3], d8);
    }
    to[row] = d8[7];
}

// Phase 2: recompute distances (identical MFMA path on identical packed data);
// count pairs below both row-thresholds.
__global__ __launch_bounds__(256, 4) void count_scan(const bf16x8* __restrict__ pkX,
                                                     const float* __restrict__ sqX,
                                                     const float* __restrict__ tX,
                                                     const bf16x8* __restrict__ pkZ,
                                                     const float* __restrict__ sqZ,
                                                     const float* __restrict__ tZ,
                                                     int* __restrict__ partial) {
    __shared__ char smem[40960];
    bf16x8(*sbX)[TB * 4 * 64] = reinterpret_cast<bf16x8(*)[TB * 4 * 64]>(smem);
    bf16x8(*sbZ)[TB * 64] = reinterpret_cast<bf16x8(*)[TB * 64]>(smem + 32768);
    __shared__ int wsum[WAVES];

    const int t = threadIdx.x;
    const int lane = t & 63;
    const int w = __builtin_amdgcn_readfirstlane(t >> 6);
    const int qt0 = blockIdx.x * QT_PER_BLOCK + w * NQ;
    const int js = blockIdx.y;
    const int t0 = js * JTILES;
    const int lrow = lane & 15;
    const int jr = (lane >> 4) * 4;

    bf16x8 bfX[NQ][4];
    bf16x8 bfZ[NQ];
    float tx[NQ], tz[NQ];
#pragma unroll
    for (int q = 0; q < NQ; ++q) {
#pragma unroll
        for (int kb = 0; kb < 4; ++kb) bfX[q][kb] = pkX[((size_t)(qt0 + q) * 4 + kb) * 64 + lane];
        bfZ[q] = pkZ[(size_t)(qt0 + q) * 64 + lane];
        tx[q] = tX[(qt0 + q) * 16 + lrow];
        tz[q] = tZ[(qt0 + q) * 16 + lrow];
    }

    {
        const size_t gx = (size_t)t0 * 4 * 64;
        const size_t gz = (size_t)t0 * 64;
#pragma unroll
        for (int s = 0; s < 4; ++s) sbX[0][t + s * 256] = pkX[gx + t + s * 256];
        sbZ[0][t] = pkZ[gz + t];
    }
    __syncthreads();

    int c = 0;
    int cur = 0;
    bf16x8 rx[4], rz;
    for (int b = 0; b < NB; ++b) {
        if (b + 1 < NB) {
            const size_t gx = (size_t)(t0 + (b + 1) * TB) * 4 * 64;
            const size_t gz = (size_t)(t0 + (b + 1) * TB) * 64;
#pragma unroll
            for (int s = 0; s < 4; ++s) rx[s] = pkX[gx + t + s * 256];
            rz = pkZ[gz + t];
        }
#pragma unroll
        for (int u = 0; u < TB; ++u) {
            const int tt = t0 + b * TB + u;
            f32x4 accX[NQ], accZ[NQ];
#pragma unroll
            for (int q = 0; q < NQ; ++q) {
                accX[q] = (f32x4){0.f, 0.f, 0.f, 0.f};
                accZ[q] = (f32x4){0.f, 0.f, 0.f, 0.f};
            }
#pragma unroll
            for (int kb = 0; kb < 4; ++kb) {
                bf16x8 af = sbX[cur][u * 256 + kb * 64 + lane];
#pragma unroll
                for (int q = 0; q < NQ; ++q)
                    accX[q] = __builtin_amdgcn_mfma_f32_16x16x32_bf16(af, bfX[q][kb], accX[q], 0, 0, 0);
            }
            {
                bf16x8 afZ = sbZ[cur][u * 64 + lane];
#pragma unroll
                for (int q = 0; q < NQ; ++q)
                    accZ[q] = __builtin_amdgcn_mfma_f32_16x16x32_bf16(afZ, bfZ[q], accZ[q], 0, 0, 0);
            }
            f32x4 sx4 = *reinterpret_cast<const f32x4*>(sqX + tt * 16 + jr);
            f32x4 sz4 = *reinterpret_cast<const f32x4*>(sqZ + tt * 16 + jr);
#pragma unroll
            for (int q = 0; q < NQ; ++q) {
                if (tt == qt0 + q) {
#pragma unroll
                    for (int r = 0; r < 4; ++r) {
                        float dx = fmaf(-2.f, accX[q][r], sx4[r]);
                        float dz = fmaf(-2.f, accZ[q][r], sz4[r]);
                        c += (dx <= tx[q] && dz <= tz[q] && (jr + r != lrow)) ? 1 : 0;
                    }
                } else {
#pragma unroll
                    for (int r = 0; r < 4; ++r) {
                        float dx = fmaf(-2.f, accX[q][r], sx4[r]);
                        float dz = fmaf(-2.f, accZ[q][r], sz4[r]);
                        c += (dx <= tx[q] && dz <= tz[q]) ? 1 : 0;
                    }
                }
            }
        }
        if (b + 1 < NB) {
#pragma unroll
            for (int s = 0; s < 4; ++s) sbX[cur ^ 1][t + s * 256] = rx[s];
            sbZ[cur ^ 1][t] = rz;
        }
        __syncthreads();
        cur ^= 1;
    }

#pragma unroll
    for (int o = 32; o > 0; o >>= 1) c += __shfl_down(c, o);
    if (lane == 0) wsum[w] = c;
    __syncthreads();
    if (t == 0)
        partial[blockIdx.y * NBX + blockIdx.x] = wsum[0] + wsum[1] + wsum[2] + wsum[3];
}

__global__ void finalize_kernel(const int* __restrict__ partial, float* __restrict__ out) {
    int v = 0;
    for (int k = threadIdx.x; k < NPART; k += 256) v += partial[k];
#pragma unroll
    for (int o = 32; o > 0; o >>= 1) v += __shfl_down(v, o);
    __shared__ int wsum[4];
    if ((threadIdx.x & 63) == 0) wsum[threadIdx.x >> 6] = v;
    __syncthreads();
    if (threadIdx.x == 0) {
        // loss = 100 * (2*K*N - 2*matches) / N^2  (exact in double)
        double m = (double)(wsum[0] + wsum[1] + wsum[2] + wsum[3]);
        out[0] = (float)((2.0 * KNN * N_PTS - 2.0 * m) * 100.0 / ((double)N_PTS * (double)N_PTS));
    }
}

extern "C" void kernel_launch(void* const* d_in, const int* in_sizes, int n_in,
                              void* d_out, int out_size, void* d_ws, size_t ws_size,
                              hipStream_t stream) {
    const float* X = (const float*)d_in[0];  // 8192 x 128
    const float* Z = (const float*)d_in[1];  // 8192 x 32
    float* out = (float*)d_out;
    char* ws = (char*)d_ws;

    bf16x8* pkX = (bf16x8*)(ws);                                // 2 MB
    bf16x8* pkZ = (bf16x8*)(ws + 2097152);                      // 512 KB
    float* sqX = (float*)(ws + 2621440);                        // 32 KB
    float* sqZ = (float*)(ws + 2654208);                        // 32 KB
    float* pdX = (float*)(ws + 2686976);                        // 4 MB (js-major)
    float* pdZ = (float*)(ws + 11075584);                       // 4 MB
    float* tX = (float*)(ws + 19464192);                        // 32 KB
    float* tZ = (float*)(ws + 19496960);                        // 32 KB
    int* partial = (int*)(ws + 19529728);                       // 8 KB

    prep_sq<128><<<N_PTS / 4, 256, 0, stream>>>(X, sqX);
    prep_sq<32><<<N_PTS / 4, 256, 0, stream>>>(Z, sqZ);
    pack_kernel<128><<<NTILE, 256, 0, stream>>>(X, pkX);
    pack_kernel<32><<<NTILE / 4, 256, 0, stream>>>(Z, pkZ);
    thresh_scan_xz<<<dim3(NBX, JSPLIT), 256, 0, stream>>>(pkX, sqX, pdX, pkZ, sqZ, pdZ);
    thresh_merge<<<dim3(N_PTS / 256, 2), 256, 0, stream>>>(pdX, tX, pdZ, tZ);
    count_scan<<<dim3(NBX, JSPLIT), 256, 0, stream>>>(pkX, sqX, tX, pkZ, sqZ, tZ, partial);
    finalize_kernel<<<1, 256, 0, stream>>>(partial, out);
}